// Round 6
// baseline (276.051 us; speedup 1.0000x reference)
//
#include <hip/hip_runtime.h>
#include <hip/hip_bf16.h>

typedef __attribute__((ext_vector_type(8))) short short8;
typedef __attribute__((ext_vector_type(4))) float f32x4;
typedef __attribute__((ext_vector_type(4))) float float4v;

#define NPB 256        // nodes per bucket (dst >> 8)
#define PBLK 256       // partition blocks
#define SCAN_TILE 1024

// ---------------- phase 1: per-(block,bucket) histogram ----------------
__global__ __launch_bounds__(256) void p1_hist(const int* __restrict__ dst,
                                               int* __restrict__ MT, int E, int NB, int chunk) {
    __shared__ int h[512];
    int t = threadIdx.x, p = blockIdx.x;
    for (int i = t; i < NB; i += 256) h[i] = 0;
    __syncthreads();
    int beg = p * chunk, end = min(beg + chunk, E);
    for (int e = beg + t; e < end; e += 256) atomicAdd(&h[dst[e] >> 8], 1);
    __syncthreads();
    for (int b = t; b < NB; b += 256) MT[b * PBLK + p] = h[b];
}

// ---------------- device-wide exclusive scan (1024-elem tiles) ----------------
__global__ __launch_bounds__(256) void scanA_kernel(const int* __restrict__ in,
                                                    int* __restrict__ out,
                                                    int* __restrict__ blocksums, int n) {
    __shared__ int sums[256];
    int t = threadIdx.x;
    int base = blockIdx.x * SCAN_TILE + t * 4;
    int v0 = (base + 0 < n) ? in[base + 0] : 0;
    int v1 = (base + 1 < n) ? in[base + 1] : 0;
    int v2 = (base + 2 < n) ? in[base + 2] : 0;
    int v3 = (base + 3 < n) ? in[base + 3] : 0;
    sums[t] = v0 + v1 + v2 + v3;
    __syncthreads();
    for (int off = 1; off < 256; off <<= 1) {
        int add = (t >= off) ? sums[t - off] : 0;
        __syncthreads();
        sums[t] += add;
        __syncthreads();
    }
    int run = (t == 0) ? 0 : sums[t - 1];
    if (base + 0 < n) out[base + 0] = run; run += v0;
    if (base + 1 < n) out[base + 1] = run; run += v1;
    if (base + 2 < n) out[base + 2] = run; run += v2;
    if (base + 3 < n) out[base + 3] = run;
    if (t == 255) blocksums[blockIdx.x] = sums[255];
}

__global__ __launch_bounds__(256) void scanB_kernel(int* __restrict__ blocksums, int nb) {
    __shared__ int sums[256];
    int t = threadIdx.x;
    sums[t] = (t < nb) ? blocksums[t] : 0;
    __syncthreads();
    for (int off = 1; off < 256; off <<= 1) {
        int add = (t >= off) ? sums[t - off] : 0;
        __syncthreads();
        sums[t] += add;
        __syncthreads();
    }
    if (t < nb) blocksums[t] = (t == 0) ? 0 : sums[t - 1];
}

__global__ __launch_bounds__(256) void scanC_kernel(int* __restrict__ data,
                                                    const int* __restrict__ blocksums, int n) {
    int i = blockIdx.x * 256 + threadIdx.x;
    if (i < n) data[i] += blocksums[i / SCAN_TILE];
}

// ---------------- phase 2: partition edges into buckets (LDS cursors only) ----------------
__global__ __launch_bounds__(256) void p2_part(const int* __restrict__ src,
                                               const int* __restrict__ dst,
                                               const float* __restrict__ ew,
                                               const int* __restrict__ MTs,
                                               int* __restrict__ pp, float* __restrict__ pw,
                                               int E, int NB, int chunk) {
    __shared__ int cur[512];
    int t = threadIdx.x, p = blockIdx.x;
    for (int b = t; b < NB; b += 256) cur[b] = MTs[b * PBLK + p];
    __syncthreads();
    int beg = p * chunk, end = min(beg + chunk, E);
    for (int e = beg + t; e < end; e += 256) {
        int d = dst[e];
        int b = d >> 8;
        int pos = atomicAdd(&cur[b], 1);
        pp[pos] = src[e] | ((d & 255) << 20);   // src < 2^20, dlocal in [0,256)
        pw[pos] = ew[e];
    }
}

// ---------------- phase 3: per-bucket exact CSR + degree + dinv ----------------
__global__ __launch_bounds__(256) void p3_bucket(const int* __restrict__ pp,
                                                 const float* __restrict__ pw,
                                                 const int* __restrict__ MTs,
                                                 int* __restrict__ srcs,
                                                 float* __restrict__ ews,
                                                 int* __restrict__ rowptr,
                                                 float* __restrict__ dinv,
                                                 int E, int N, int NB) {
    __shared__ int cnt[256];
    __shared__ float wd[256];
    __shared__ int ls[256];
    __shared__ int cur[256];
    int t = threadIdx.x, b = blockIdx.x;
    int beg = MTs[b * PBLK];
    int end = (b == NB - 1) ? E : MTs[(b + 1) * PBLK];
    cnt[t] = 0;
    wd[t] = 0.0f;
    __syncthreads();
    for (int e = beg + t; e < end; e += 256) {
        int v = pp[e];
        int dl = v >> 20;
        atomicAdd(&cnt[dl], 1);
        atomicAdd(&wd[dl], pw[e]);
    }
    __syncthreads();
    ls[t] = cnt[t];
    __syncthreads();
    for (int off = 1; off < 256; off <<= 1) {
        int add = (t >= off) ? ls[t - off] : 0;
        __syncthreads();
        ls[t] += add;
        __syncthreads();
    }
    int excl = (t == 0) ? 0 : ls[t - 1];
    int node = b * NPB + t;
    if (node < N) {
        rowptr[node] = beg + excl;
        dinv[node] = rsqrtf(1.0f + wd[t]);   // +1 = self-loop weight
    }
    cur[t] = beg + excl;
    if (b == NB - 1 && t == 0) rowptr[N] = E;
    __syncthreads();
    for (int e = beg + t; e < end; e += 256) {
        int v = pp[e];
        int dl = v >> 20;
        int pos = atomicAdd(&cur[dl], 1);
        srcs[pos] = v & 0xFFFFF;
        ews[pos] = pw[e];
    }
}

// ---------------- MFMA GEMM: Fs = bf16( dinv .* (A @ W) ) ----------------
// Split precision: A ~= Ahi+Alo, W ~= Whi+Wlo (bf16); P = Ahi*Whi + Alo*Whi + Ahi*Wlo.
// Wave-independent streaming: W (hi/lo, transposed, swizzled) staged once in LDS
// (64 KB, one barrier); each wave owns 16-row panels grid-strided, loading A
// fragments straight from global into regs (no panel barriers, no A LDS).
// 16x16x32 bf16 MFMA; A: row=lane&15, k=8*(lane>>4); C/D: col=lane&15, row=(lane>>4)*4+reg.
__global__ __launch_bounds__(256) void gemm_mfma(const float* __restrict__ A,
                                                 const float* __restrict__ W,
                                                 const float* __restrict__ dinv,
                                                 __hip_bfloat16* __restrict__ Fs,
                                                 int nrows) {
    __shared__ short sWhi[128 * 128];
    __shared__ short sWlo[128 * 128];

    const int t = threadIdx.x;

    // ---- stage whole W: transposed [col][k], hi/lo split, swizzled ----
    for (int i = t; i < 128 * 128; i += 256) {
        int k = i >> 7, c = i & 127;
        float w = W[i];
        __hip_bfloat16 h = __float2bfloat16(w);
        float hf = __bfloat162float(h);
        __hip_bfloat16 l = __float2bfloat16(w - hf);
        int idx = (c * 128 + k) ^ ((c & 7) << 3);
        sWhi[idx] = (short)__bfloat16_as_ushort(h);
        sWlo[idx] = (short)__bfloat16_as_ushort(l);
    }
    __syncthreads();   // the only barrier

    const int lane = t & 63;
    const int fr = lane & 15;      // frag row/col index
    const int kq = lane >> 4;      // 0..3 -> k sub-offset 8*kq

    const int gw = blockIdx.x * 4 + (t >> 6);     // global wave id
    const int nw = gridDim.x * 4;
    const int npan = (nrows + 15) / 16;

    for (int p = gw; p < npan; p += nw) {
        const int arow = p * 16 + fr;
        const bool valid = arow < nrows;

        // ---- load A fragments global->regs, convert hi/lo ----
        short8 ahi[4], alo[4];
#pragma unroll
        for (int ks = 0; ks < 4; ++ks) {
            float4v v0 = {0.f, 0.f, 0.f, 0.f}, v1 = {0.f, 0.f, 0.f, 0.f};
            if (valid) {
                const float4v* Ag = (const float4v*)(A + (size_t)arow * 128 + ks * 32 + kq * 8);
                v0 = Ag[0];
                v1 = Ag[1];
            }
            float vf[8] = {v0[0], v0[1], v0[2], v0[3], v1[0], v1[1], v1[2], v1[3]};
            short8 h8, l8;
#pragma unroll
            for (int j = 0; j < 8; ++j) {
                __hip_bfloat16 h = __float2bfloat16(vf[j]);
                h8[j] = (short)__bfloat16_as_ushort(h);
                l8[j] = (short)__bfloat16_as_ushort(__float2bfloat16(vf[j] - __bfloat162float(h)));
            }
            ahi[ks] = h8;
            alo[ks] = l8;
        }

        // ---- compute: 16 rows x 128 cols ----
        f32x4 acc[8];
#pragma unroll
        for (int fc = 0; fc < 8; ++fc) acc[fc] = (f32x4){0.f, 0.f, 0.f, 0.f};

#pragma unroll
        for (int ks = 0; ks < 4; ++ks) {
            int ak = ks * 32 + 8 * kq;
#pragma unroll
            for (int fc = 0; fc < 8; ++fc) {
                int c = fc * 16 + fr;
                int bidx = (c * 128 + ak) ^ ((c & 7) << 3);
                short8 bhi = *(short8*)&sWhi[bidx];
                short8 blo = *(short8*)&sWlo[bidx];
                acc[fc] = __builtin_amdgcn_mfma_f32_16x16x32_bf16(ahi[ks], bhi, acc[fc], 0, 0, 0);
                acc[fc] = __builtin_amdgcn_mfma_f32_16x16x32_bf16(alo[ks], bhi, acc[fc], 0, 0, 0);
                acc[fc] = __builtin_amdgcn_mfma_f32_16x16x32_bf16(ahi[ks], blo, acc[fc], 0, 0, 0);
            }
        }

        // ---- epilogue: scale by dinv[row], convert bf16, store ----
        int rb = p * 16 + kq * 4;
#pragma unroll
        for (int r = 0; r < 4; ++r) {
            int grow = rb + r;
            if (grow < nrows) {
                float s = dinv[grow];
#pragma unroll
                for (int fc = 0; fc < 8; ++fc) {
                    int col = fc * 16 + fr;
                    Fs[(size_t)grow * 128 + col] = __float2bfloat16(s * acc[fc][r]);
                }
            }
        }
    }
}

// ---------------- aggregation over bf16 scaled features ----------------
// out[d] = relu( dinv[d] * ( sum_e ew[e]*Fs[src_e] + Fs[d] ) + bias )
__global__ __launch_bounds__(256) void agg_kernel(const __hip_bfloat16* __restrict__ F,
                                                  const int* __restrict__ rowptr,
                                                  const int* __restrict__ srcs,
                                                  const float* __restrict__ ews,
                                                  const float* __restrict__ dinv,
                                                  const float* __restrict__ bias,
                                                  float* __restrict__ out, int n) {
    const unsigned* Fu = (const unsigned*)F;   // one uint = 2 bf16 cols
    int wid  = (blockIdx.x * 256 + threadIdx.x) >> 6;
    int lane = threadIdx.x & 63;
    int node = __builtin_amdgcn_readfirstlane(wid);
    if (node >= n) return;

    int beg = rowptr[node];
    int end = rowptr[node + 1];
    float di = dinv[node];

    unsigned sv = Fu[(size_t)node * 64 + lane];
    float accx = __uint_as_float(sv << 16);
    float accy = __uint_as_float(sv & 0xFFFF0000u);

    int e = beg;
    for (; e + 4 <= end; e += 4) {
        int s0 = srcs[e + 0], s1 = srcs[e + 1], s2 = srcs[e + 2], s3 = srcs[e + 3];
        float w0 = ews[e + 0], w1 = ews[e + 1], w2 = ews[e + 2], w3 = ews[e + 3];
        unsigned v0 = Fu[(size_t)s0 * 64 + lane];
        unsigned v1 = Fu[(size_t)s1 * 64 + lane];
        unsigned v2 = Fu[(size_t)s2 * 64 + lane];
        unsigned v3 = Fu[(size_t)s3 * 64 + lane];
        accx += w0 * __uint_as_float(v0 << 16);
        accy += w0 * __uint_as_float(v0 & 0xFFFF0000u);
        accx += w1 * __uint_as_float(v1 << 16);
        accy += w1 * __uint_as_float(v1 & 0xFFFF0000u);
        accx += w2 * __uint_as_float(v2 << 16);
        accy += w2 * __uint_as_float(v2 & 0xFFFF0000u);
        accx += w3 * __uint_as_float(v3 << 16);
        accy += w3 * __uint_as_float(v3 & 0xFFFF0000u);
    }
    for (; e < end; ++e) {
        int s = srcs[e];
        float w = ews[e];
        unsigned v = Fu[(size_t)s * 64 + lane];
        accx += w * __uint_as_float(v << 16);
        accy += w * __uint_as_float(v & 0xFFFF0000u);
    }

    float2 bv = *(const float2*)(bias + 2 * lane);
    accx = fmaxf(di * accx + bv.x, 0.0f);
    accy = fmaxf(di * accy + bv.y, 0.0f);
    *(float2*)(out + (size_t)node * 128 + 2 * lane) = make_float2(accx, accy);
}

// ---------------- launcher ----------------

extern "C" void kernel_launch(void* const* d_in, const int* in_sizes, int n_in,
                              void* d_out, int out_size, void* d_ws, size_t ws_size,
                              hipStream_t stream) {
    const float* x  = (const float*)d_in[0];
    const int*   ei = (const int*)d_in[1];
    const float* ew = (const float*)d_in[2];
    const float* W1 = (const float*)d_in[3];
    const float* b1 = (const float*)d_in[4];
    const float* W2 = (const float*)d_in[5];
    const float* b2 = (const float*)d_in[6];
    float* out = (float*)d_out;

    const int N = in_sizes[0] / 128;
    const int E = in_sizes[2];
    const int* src = ei;
    const int* dst = ei + E;

    const int NB = (N + NPB - 1) / NPB;        // buckets (391 for N=100k)
    const int L  = NB * PBLK;                  // count-matrix length
    const int chunk = (E + PBLK - 1) / PBLK;

    // workspace layout. pp/pw alias the bf16 feature buffer (dead before GEMM writes it).
    __hip_bfloat16* bufB = (__hip_bfloat16*)d_ws;      // N*128 bf16 (25.6 MB)
    int*   pp     = (int*)d_ws;                        // E ints   (alias)
    float* pw     = (float*)(pp + E);                  // E floats (alias)
    int*   srcs   = (int*)((char*)d_ws + (size_t)N * 128 * sizeof(__hip_bfloat16));  // E
    float* ews    = (float*)(srcs + E);        // E
    int*   rowptr = (int*)(ews + E);           // N+1
    float* dinv   = (float*)(rowptr + N + 1);  // N
    int*   MT     = (int*)(dinv + N);          // L
    int*   MTs    = MT + L;                    // L
    int*   bsums  = MTs + L;                   // ceil(L/1024)

    const int nb_scan = (L + SCAN_TILE - 1) / SCAN_TILE;

    hipLaunchKernelGGL(p1_hist, dim3(PBLK), dim3(256), 0, stream, dst, MT, E, NB, chunk);
    hipLaunchKernelGGL(scanA_kernel, dim3(nb_scan), dim3(256), 0, stream, MT, MTs, bsums, L);
    hipLaunchKernelGGL(scanB_kernel, dim3(1), dim3(256), 0, stream, bsums, nb_scan);
    hipLaunchKernelGGL(scanC_kernel, dim3((L + 255) / 256), dim3(256), 0, stream, MTs, bsums, L);
    hipLaunchKernelGGL(p2_part, dim3(PBLK), dim3(256), 0, stream, src, dst, ew, MTs, pp, pw, E, NB, chunk);
    hipLaunchKernelGGL(p3_bucket, dim3(NB), dim3(256), 0, stream, pp, pw, MTs, srcs, ews, rowptr, dinv, E, N, NB);

    // layer 1: Fs = bf16(dinv .* (x@W1)) -> bufB ; h = relu(dinv.*(agg(bufB))+b1) -> d_out
    hipLaunchKernelGGL(gemm_mfma, dim3(512), dim3(256), 0, stream, x, W1, dinv, bufB, N);
    hipLaunchKernelGGL(agg_kernel, dim3((N + 3) / 4), dim3(256), 0, stream, bufB, rowptr, srcs, ews, dinv, b1, out, N);

    // layer 2: Fs = bf16(dinv .* (h@W2)) -> bufB ; out = relu(dinv.*(agg(bufB))+b2) -> d_out
    hipLaunchKernelGGL(gemm_mfma, dim3(512), dim3(256), 0, stream, out, W2, dinv, bufB, N);
    hipLaunchKernelGGL(agg_kernel, dim3((N + 3) / 4), dim3(256), 0, stream, bufB, rowptr, srcs, ews, dinv, b2, out, N);
}